// Round 2
// baseline (421.631 us; speedup 1.0000x reference)
//
#include <hip/hip_runtime.h>

#define N_NODES   100000
#define N_EDGES   1600000
#define N_CLIQUES 250000

typedef unsigned short ushort4v __attribute__((ext_vector_type(4)));
typedef unsigned short ushort8v __attribute__((ext_vector_type(8)));

__device__ __forceinline__ float bf2f(unsigned short u) {
    return __uint_as_float(((unsigned int)u) << 16);
}
__device__ __forceinline__ unsigned short f2bf(float f) {
    unsigned int u = __float_as_uint(f);
    u += 0x7FFFu + ((u >> 16) & 1u);
    return (unsigned short)(u >> 16);
}

__global__ __launch_bounds__(256) void zero_kernel(float* __restrict__ p, int n) {
    int i = blockIdx.x * 256 + threadIdx.x;
    if (i < n) p[i] = 0.0f;
}

// ---- Projection: q,k,v = x@W + b, stored interleaved qkv[node][3][128] as bf16 ----
// Block: 64 nodes, 256 threads. LDS: xT (k-major, XOR-swizzled), per-matrix weight tile.
__global__ __launch_bounds__(256) void proj_kernel(
    const float* __restrict__ x,
    const float* __restrict__ Qw, const float* __restrict__ Qb,
    const float* __restrict__ Kw, const float* __restrict__ Kb,
    const float* __restrict__ Vw, const float* __restrict__ Vb,
    unsigned short* __restrict__ qkv)
{
    __shared__ unsigned short xT[128][64];   // [k][m-swizzled] 16KB
    __shared__ unsigned short wB[128][128];  // [k][c]           32KB
    __shared__ float bias[128];

    const int tid = threadIdx.x;
    const int node0 = blockIdx.x * 64;

    // load x tile, transpose to k-major with XOR swizzle on m-blocks of 4
    {
        const int mi = tid >> 5;            // 0..7
        const int k4 = (tid & 31) * 4;      // k>>2 == tid&31
        const int sw = tid & 15;            // (k>>2)&15
        #pragma unroll
        for (int it = 0; it < 8; ++it) {
            int m = mi + it * 8;
            int node = node0 + m;
            float4 v;
            if (node < N_NODES) v = *(const float4*)(x + (size_t)node * 128 + k4);
            else { v.x = 0.f; v.y = 0.f; v.z = 0.f; v.w = 0.f; }
            int col = 4 * ((m >> 2) ^ sw) + (m & 3);
            xT[k4 + 0][col] = f2bf(v.x);
            xT[k4 + 1][col] = f2bf(v.y);
            xT[k4 + 2][col] = f2bf(v.z);
            xT[k4 + 3][col] = f2bf(v.w);
        }
    }

    const int tm = tid >> 4;   // 0..15 -> nodes tm*4..+3
    const int tc = tid & 15;   // 0..15 -> cols tc*8..+7

    for (int t = 0; t < 3; ++t) {
        __syncthreads();   // xT ready (t=0); previous tile consumers done (t>0)
        const float* W = (t == 0) ? Qw : ((t == 1) ? Kw : Vw);
        const float* B = (t == 0) ? Qb : ((t == 1) ? Kb : Vb);
        {
            int k = tid >> 5;
            const int c4 = (tid & 31) * 4;
            #pragma unroll
            for (int it = 0; it < 16; ++it, k += 8) {
                float4 v = *(const float4*)(W + (size_t)k * 128 + c4);
                wB[k][c4 + 0] = f2bf(v.x);
                wB[k][c4 + 1] = f2bf(v.y);
                wB[k][c4 + 2] = f2bf(v.z);
                wB[k][c4 + 3] = f2bf(v.w);
            }
            if (tid < 128) bias[tid] = B[tid];
        }
        __syncthreads();

        float acc[4][8];
        #pragma unroll
        for (int i = 0; i < 4; ++i)
            #pragma unroll
            for (int j = 0; j < 8; ++j) acc[i][j] = 0.f;

        #pragma unroll 4
        for (int k = 0; k < 128; ++k) {
            ushort4v xv = *(const ushort4v*)&xT[k][4 * (tm ^ ((k >> 2) & 15))];
            ushort8v wv = *(const ushort8v*)&wB[k][tc * 8];
            float xf[4], wf[8];
            #pragma unroll
            for (int i = 0; i < 4; ++i) xf[i] = bf2f(xv[i]);
            #pragma unroll
            for (int j = 0; j < 8; ++j) wf[j] = bf2f(wv[j]);
            #pragma unroll
            for (int i = 0; i < 4; ++i)
                #pragma unroll
                for (int j = 0; j < 8; ++j)
                    acc[i][j] = fmaf(xf[i], wf[j], acc[i][j]);
        }

        #pragma unroll
        for (int mi = 0; mi < 4; ++mi) {
            int node = node0 + tm * 4 + mi;
            if (node < N_NODES) {
                ushort8v ov;
                #pragma unroll
                for (int j = 0; j < 8; ++j)
                    ov[j] = f2bf(acc[mi][j] + bias[tc * 8 + j]);
                *(ushort8v*)(qkv + ((size_t)node * 3 + t) * 128 + tc * 8) = ov;
            }
        }
    }
}

// ---- Clique contraction: 16 lanes per clique, 8 dims per lane ----
// Writes diagA2 (f32) directly; atomically accumulates diagA1 into d_out region.
__global__ __launch_bounds__(256) void clique_kernel(
    const unsigned short* __restrict__ qkv,
    const int* __restrict__ tci,      // [3][N_CLIQUES]
    const int* __restrict__ d1row1,   // [3*N_CLIQUES]
    float* __restrict__ outA1,
    float* __restrict__ outA2)
{
    const int tid = threadIdx.x;
    const int lane16 = tid & 15;
    const int cliq = (blockIdx.x * 256 + tid) >> 4;   // grid exact: 15625*16 = 250000

    const int ni = tci[cliq];
    const int nj = tci[N_CLIQUES + cliq];
    const int nk = tci[2 * N_CLIQUES + cliq];
    const int d0 = lane16 * 8;

    const ushort8v qi = *(const ushort8v*)(qkv + (size_t)ni * 384 +       d0);
    const ushort8v ki = *(const ushort8v*)(qkv + (size_t)ni * 384 + 128 + d0);
    const ushort8v vi = *(const ushort8v*)(qkv + (size_t)ni * 384 + 256 + d0);
    const ushort8v qj = *(const ushort8v*)(qkv + (size_t)nj * 384 +       d0);
    const ushort8v kj = *(const ushort8v*)(qkv + (size_t)nj * 384 + 128 + d0);
    const ushort8v vj = *(const ushort8v*)(qkv + (size_t)nj * 384 + 256 + d0);
    const ushort8v qk = *(const ushort8v*)(qkv + (size_t)nk * 384 +       d0);
    const ushort8v kk = *(const ushort8v*)(qkv + (size_t)nk * 384 + 128 + d0);
    const ushort8v vk = *(const ushort8v*)(qkv + (size_t)nk * 384 + 256 + d0);

    float s = 0.f;
    #pragma unroll
    for (int d = 0; d < 8; ++d) {
        float Qi = bf2f(qi[d]), Qj = bf2f(qj[d]), Qk = bf2f(qk[d]);
        float Ki = bf2f(ki[d]), Kj = bf2f(kj[d]), Kk = bf2f(kk[d]);
        float Vi = bf2f(vi[d]), Vj = bf2f(vj[d]), Vk = bf2f(vk[d]);
        s = fmaf(Qi, fmaf(Kj, Vk, Kk * Vj), s);
        s = fmaf(Qj, fmaf(Kk, Vi, Ki * Vk), s);
        s = fmaf(Qk, fmaf(Ki, Vj, Kj * Vi), s);
    }
    s += __shfl_xor(s, 1);
    s += __shfl_xor(s, 2);
    s += __shfl_xor(s, 4);
    s += __shfl_xor(s, 8);

    float score = expf(s * (1.0f / 24.0f));
    if (lane16 == 0) outA2[cliq] = score;
    if (lane16 < 3) {
        atomicAdd(outA1 + d1row1[3 * cliq + lane16], score);
    }
}

// ---- Edge scatter: read final diagA1, accumulate diagA0 ----
__global__ __launch_bounds__(256) void edge_kernel(
    const float* __restrict__ outA1,
    const int* __restrict__ d0row1,
    float* __restrict__ outA0)
{
    int e = blockIdx.x * 256 + threadIdx.x;
    if (e < N_EDGES) {
        float v = outA1[e];
        int2 tg = *(const int2*)(d0row1 + 2 * (size_t)e);
        atomicAdd(outA0 + tg.x, v);
        atomicAdd(outA0 + tg.y, v);
    }
}

extern "C" void kernel_launch(void* const* d_in, const int* in_sizes, int n_in,
                              void* d_out, int out_size, void* d_ws, size_t ws_size,
                              hipStream_t stream)
{
    const float* x  = (const float*)d_in[0];
    const int*   d0i = (const int*)d_in[2];     // [2][2*N_EDGES]
    const int*   tci = (const int*)d_in[3];     // [3][N_CLIQUES]
    const int*   d1i = (const int*)d_in[4];     // [2][3*N_CLIQUES]
    const float* Qw = (const float*)d_in[5];
    const float* Qb = (const float*)d_in[6];
    const float* Kw = (const float*)d_in[7];
    const float* Kb = (const float*)d_in[8];
    const float* Vw = (const float*)d_in[9];
    const float* Vb = (const float*)d_in[10];

    const int* d0row1 = d0i + 2 * (size_t)N_EDGES;
    const int* d1row1 = d1i + 3 * (size_t)N_CLIQUES;

    // workspace: qkv bf16 [100000][3][128] = 76.8 MB
    unsigned short* qkv = (unsigned short*)d_ws;

    // outputs are FLOAT32, concatenated (diagA0, diagA1, diagA2)
    float* outA0 = (float*)d_out;
    float* outA1 = outA0 + N_NODES;
    float* outA2 = outA0 + N_NODES + N_EDGES;

    // zero the accumulated output regions (A0 + A1); A2 is pure overwrite.
    zero_kernel<<<(N_NODES + N_EDGES + 255) / 256, 256, 0, stream>>>(outA0, N_NODES + N_EDGES);
    proj_kernel<<<(N_NODES + 63) / 64, 256, 0, stream>>>(x, Qw, Qb, Kw, Kb, Vw, Vb, qkv);
    clique_kernel<<<N_CLIQUES / 16, 256, 0, stream>>>(qkv, tci, d1row1, outA1, outA2);
    edge_kernel<<<(N_EDGES + 255) / 256, 256, 0, stream>>>(outA1, d0row1, outA0);
}

// Round 3
// 298.749 us; speedup vs baseline: 1.4113x; 1.4113x over previous
//
#include <hip/hip_runtime.h>

#define N_NODES   100000
#define N_EDGES   1600000
#define N_CLIQUES 250000

typedef unsigned short ushort8v __attribute__((ext_vector_type(8)));
typedef __bf16 bf16x8 __attribute__((ext_vector_type(8)));
typedef float f32x4 __attribute__((ext_vector_type(4)));

__device__ __forceinline__ float bf2f(unsigned short u) {
    return __uint_as_float(((unsigned int)u) << 16);
}
__device__ __forceinline__ unsigned short f2bf(float f) {
    unsigned int u = __float_as_uint(f);
    u += 0x7FFFu + ((u >> 16) & 1u);
    return (unsigned short)(u >> 16);
}

__global__ __launch_bounds__(256) void zero_kernel(float* __restrict__ p, int n) {
    int i = blockIdx.x * 256 + threadIdx.x;
    if (i < n) p[i] = 0.0f;
}

// ---- prep: W [k][col] f32  ->  wt bf16 [t][col][k] (col-major for B-frag reads) ----
__global__ __launch_bounds__(256) void prep_weights(
    const float* __restrict__ Qw, const float* __restrict__ Kw,
    const float* __restrict__ Vw, unsigned short* __restrict__ wt)
{
    int idx = blockIdx.x * 256 + threadIdx.x;      // 3*128*128 = 49152
    int t = idx >> 14;
    int rem = idx & 16383;
    int col = rem >> 7;
    int k = rem & 127;
    const float* W = (t == 0) ? Qw : ((t == 1) ? Kw : Vw);
    wt[idx] = f2bf(W[k * 128 + col]);              // wt[t][col][k]
}

// ---- Projection via MFMA: qkv[node][3][128] bf16 ----
// 64 nodes/block, 4 waves (16 rows each). A-frags in regs, reused for q,k,v.
__global__ __launch_bounds__(256) void proj_mfma(
    const float* __restrict__ x,
    const unsigned short* __restrict__ wt,   // bf16 [3][128 col][128 k]
    const float* __restrict__ Qb, const float* __restrict__ Kb,
    const float* __restrict__ Vb,
    unsigned short* __restrict__ qkv)
{
    __shared__ unsigned short wS[128 * 128];  // [col][k], 16B-chunk XOR swizzled, 32KB
    __shared__ unsigned short cS[64 * 144];   // C tile [row][col], pad->stride 288B, 18.4KB
    __shared__ float biasS[128];

    const int tid  = threadIdx.x;
    const int lane = tid & 63;
    const int w    = tid >> 6;        // wave 0..3
    const int node0 = blockIdx.x * 64;
    const int arow = lane & 15;       // A row within wave tile / C col index source
    const int kg   = lane >> 4;       // 0..3 k-group

    // --- A fragments: 4 k-tiles of 32, each lane holds 8 contiguous k (bf16) ---
    bf16x8 afrag[4];
    const int myNode = node0 + w * 16 + arow;
    const bool valid = myNode < N_NODES;
    const float* xrow = x + (size_t)myNode * 128;
    #pragma unroll
    for (int kt = 0; kt < 4; ++kt) {
        float4 v0, v1;
        const int kbase = kt * 32 + kg * 8;
        if (valid) {
            v0 = *(const float4*)(xrow + kbase);
            v1 = *(const float4*)(xrow + kbase + 4);
        } else {
            v0.x = v0.y = v0.z = v0.w = 0.f;
            v1.x = v1.y = v1.z = v1.w = 0.f;
        }
        ushort8v u;
        u[0] = f2bf(v0.x); u[1] = f2bf(v0.y); u[2] = f2bf(v0.z); u[3] = f2bf(v0.w);
        u[4] = f2bf(v1.x); u[5] = f2bf(v1.y); u[6] = f2bf(v1.z); u[7] = f2bf(v1.w);
        afrag[kt] = __builtin_bit_cast(bf16x8, u);
    }

    for (int t = 0; t < 3; ++t) {
        __syncthreads();
        // stage W_t (bf16 col-major) into LDS, XOR-swizzle 16B chunks within each col row
        {
            const unsigned short* src = wt + t * 16384;
            #pragma unroll
            for (int it = 0; it < 8; ++it) {
                int i   = tid + it * 256;     // 16B chunk index, 0..2047
                int col = i >> 4;
                int ko  = i & 15;
                *(ushort8v*)&wS[col * 128 + (ko ^ (col & 7)) * 8] =
                    *(const ushort8v*)(src + i * 8);
            }
            if (tid < 128) biasS[tid] = ((t == 0) ? Qb : ((t == 1) ? Kb : Vb))[tid];
        }
        __syncthreads();

        f32x4 acc[8];
        #pragma unroll
        for (int c = 0; c < 8; ++c) acc[c] = (f32x4){0.f, 0.f, 0.f, 0.f};

        #pragma unroll
        for (int kt = 0; kt < 4; ++kt) {
            const int chunk = kt * 4 + kg;
            #pragma unroll
            for (int c = 0; c < 8; ++c) {
                const int col = c * 16 + arow;
                ushort8v bu = *(const ushort8v*)&wS[col * 128 + (chunk ^ (col & 7)) * 8];
                acc[c] = __builtin_amdgcn_mfma_f32_16x16x32_bf16(
                    afrag[kt], __builtin_bit_cast(bf16x8, bu), acc[c], 0, 0, 0);
            }
        }
        __syncthreads();

        // C frags -> LDS (+bias). D layout: col=lane&15, row=(lane>>4)*4+reg.
        #pragma unroll
        for (int c = 0; c < 8; ++c) {
            const int col = c * 16 + arow;
            const float b = biasS[col];
            #pragma unroll
            for (int r = 0; r < 4; ++r) {
                const int orow = w * 16 + kg * 4 + r;
                cS[orow * 144 + col] = f2bf(acc[c][r] + b);
            }
        }
        __syncthreads();

        // coalesced copy-out: 64 rows x 128 cols bf16
        #pragma unroll
        for (int it = 0; it < 4; ++it) {
            int i    = tid + it * 256;        // 0..1023: row*16 + 16B chunk
            int orow = i >> 4;
            int ch   = i & 15;
            int node = node0 + orow;
            if (node < N_NODES)
                *(ushort8v*)(qkv + (size_t)node * 384 + t * 128 + ch * 8) =
                    *(const ushort8v*)&cS[orow * 144 + ch * 8];
        }
    }
}

// ---- Clique contraction: 16 lanes per clique, 8 dims per lane ----
__global__ __launch_bounds__(256) void clique_kernel(
    const unsigned short* __restrict__ qkv,
    const int* __restrict__ tci,      // [3][N_CLIQUES]
    const int* __restrict__ d1row1,   // [3*N_CLIQUES]
    float* __restrict__ outA1,
    float* __restrict__ outA2)
{
    const int tid = threadIdx.x;
    const int lane16 = tid & 15;
    const int cliq = (blockIdx.x * 256 + tid) >> 4;   // grid exact: 15625*16 = 250000

    const int ni = tci[cliq];
    const int nj = tci[N_CLIQUES + cliq];
    const int nk = tci[2 * N_CLIQUES + cliq];
    const int d0 = lane16 * 8;

    const ushort8v qi = *(const ushort8v*)(qkv + (size_t)ni * 384 +       d0);
    const ushort8v ki = *(const ushort8v*)(qkv + (size_t)ni * 384 + 128 + d0);
    const ushort8v vi = *(const ushort8v*)(qkv + (size_t)ni * 384 + 256 + d0);
    const ushort8v qj = *(const ushort8v*)(qkv + (size_t)nj * 384 +       d0);
    const ushort8v kj = *(const ushort8v*)(qkv + (size_t)nj * 384 + 128 + d0);
    const ushort8v vj = *(const ushort8v*)(qkv + (size_t)nj * 384 + 256 + d0);
    const ushort8v qk = *(const ushort8v*)(qkv + (size_t)nk * 384 +       d0);
    const ushort8v kk = *(const ushort8v*)(qkv + (size_t)nk * 384 + 128 + d0);
    const ushort8v vk = *(const ushort8v*)(qkv + (size_t)nk * 384 + 256 + d0);

    float s = 0.f;
    #pragma unroll
    for (int d = 0; d < 8; ++d) {
        float Qi = bf2f(qi[d]), Qj = bf2f(qj[d]), Qk = bf2f(qk[d]);
        float Ki = bf2f(ki[d]), Kj = bf2f(kj[d]), Kk = bf2f(kk[d]);
        float Vi = bf2f(vi[d]), Vj = bf2f(vj[d]), Vk = bf2f(vk[d]);
        s = fmaf(Qi, fmaf(Kj, Vk, Kk * Vj), s);
        s = fmaf(Qj, fmaf(Kk, Vi, Ki * Vk), s);
        s = fmaf(Qk, fmaf(Ki, Vj, Kj * Vi), s);
    }
    s += __shfl_xor(s, 1);
    s += __shfl_xor(s, 2);
    s += __shfl_xor(s, 4);
    s += __shfl_xor(s, 8);

    float score = expf(s * (1.0f / 24.0f));
    if (lane16 == 0) outA2[cliq] = score;
    if (lane16 < 3) {
        atomicAdd(outA1 + d1row1[3 * cliq + lane16], score);
    }
}

// ---- Edge scatter: read final diagA1, accumulate diagA0 ----
__global__ __launch_bounds__(256) void edge_kernel(
    const float* __restrict__ outA1,
    const int* __restrict__ d0row1,
    float* __restrict__ outA0)
{
    int e = blockIdx.x * 256 + threadIdx.x;
    if (e < N_EDGES) {
        float v = outA1[e];
        int2 tg = *(const int2*)(d0row1 + 2 * (size_t)e);
        atomicAdd(outA0 + tg.x, v);
        atomicAdd(outA0 + tg.y, v);
    }
}

extern "C" void kernel_launch(void* const* d_in, const int* in_sizes, int n_in,
                              void* d_out, int out_size, void* d_ws, size_t ws_size,
                              hipStream_t stream)
{
    const float* x  = (const float*)d_in[0];
    const int*   d0i = (const int*)d_in[2];     // [2][2*N_EDGES]
    const int*   tci = (const int*)d_in[3];     // [3][N_CLIQUES]
    const int*   d1i = (const int*)d_in[4];     // [2][3*N_CLIQUES]
    const float* Qw = (const float*)d_in[5];
    const float* Qb = (const float*)d_in[6];
    const float* Kw = (const float*)d_in[7];
    const float* Kb = (const float*)d_in[8];
    const float* Vw = (const float*)d_in[9];
    const float* Vb = (const float*)d_in[10];

    const int* d0row1 = d0i + 2 * (size_t)N_EDGES;
    const int* d1row1 = d1i + 3 * (size_t)N_CLIQUES;

    // workspace: qkv bf16 [100000][3][128] = 76.8 MB | wt bf16 [3][128][128] = 96 KB
    unsigned short* qkv = (unsigned short*)d_ws;
    unsigned short* wt  = qkv + (size_t)N_NODES * 384;

    // outputs are FLOAT32, concatenated (diagA0, diagA1, diagA2)
    float* outA0 = (float*)d_out;
    float* outA1 = outA0 + N_NODES;
    float* outA2 = outA0 + N_NODES + N_EDGES;

    zero_kernel<<<(N_NODES + N_EDGES + 255) / 256, 256, 0, stream>>>(outA0, N_NODES + N_EDGES);
    prep_weights<<<192, 256, 0, stream>>>(Qw, Kw, Vw, wt);
    proj_mfma<<<(N_NODES + 63) / 64, 256, 0, stream>>>(x, wt, Qb, Kb, Vb, qkv);
    clique_kernel<<<N_CLIQUES / 16, 256, 0, stream>>>(qkv, tci, d1row1, outA1, outA2);
    edge_kernel<<<(N_EDGES + 255) / 256, 256, 0, stream>>>(outA1, d0row1, outA0);
}

// Round 4
// 182.537 us; speedup vs baseline: 2.3098x; 1.6366x over previous
//
#include <hip/hip_runtime.h>

#define N_NODES   100000
#define N_EDGES   1600000
#define N_CLIQUES 250000

typedef unsigned short ushort8v __attribute__((ext_vector_type(8)));
typedef __bf16 bf16x8 __attribute__((ext_vector_type(8)));
typedef float f32x4 __attribute__((ext_vector_type(4)));

__device__ __forceinline__ float bf2f(unsigned short u) {
    return __uint_as_float(((unsigned int)u) << 16);
}
__device__ __forceinline__ unsigned short f2bf(float f) {
    unsigned int u = __float_as_uint(f);
    u += 0x7FFFu + ((u >> 16) & 1u);
    return (unsigned short)(u >> 16);
}

__global__ __launch_bounds__(256) void zero_kernel(float* __restrict__ p, int n) {
    int i = blockIdx.x * 256 + threadIdx.x;
    if (i < n) p[i] = 0.0f;
}

// ---- prep: W [k][col] f32  ->  wt bf16 [t][col][k] (col-major for B-frag reads) ----
__global__ __launch_bounds__(256) void prep_weights(
    const float* __restrict__ Qw, const float* __restrict__ Kw,
    const float* __restrict__ Vw, unsigned short* __restrict__ wt)
{
    int idx = blockIdx.x * 256 + threadIdx.x;      // 3*128*128 = 49152
    int t = idx >> 14;
    int rem = idx & 16383;
    int col = rem >> 7;
    int k = rem & 127;
    const float* W = (t == 0) ? Qw : ((t == 1) ? Kw : Vw);
    wt[idx] = f2bf(W[k * 128 + col]);              // wt[t][col][k]
}

// ---- Projection via MFMA: qkv[node][3][128] bf16 ----
__global__ __launch_bounds__(256) void proj_mfma(
    const float* __restrict__ x,
    const unsigned short* __restrict__ wt,   // bf16 [3][128 col][128 k]
    const float* __restrict__ Qb, const float* __restrict__ Kb,
    const float* __restrict__ Vb,
    unsigned short* __restrict__ qkv)
{
    __shared__ unsigned short wS[128 * 128];  // [col][k], 16B-chunk XOR swizzled, 32KB
    __shared__ unsigned short cS[64 * 144];   // C tile [row][col], padded stride
    __shared__ float biasS[128];

    const int tid  = threadIdx.x;
    const int lane = tid & 63;
    const int w    = tid >> 6;        // wave 0..3
    const int node0 = blockIdx.x * 64;
    const int arow = lane & 15;
    const int kg   = lane >> 4;       // 0..3 k-group

    bf16x8 afrag[4];
    const int myNode = node0 + w * 16 + arow;
    const bool valid = myNode < N_NODES;
    const float* xrow = x + (size_t)myNode * 128;
    #pragma unroll
    for (int kt = 0; kt < 4; ++kt) {
        float4 v0, v1;
        const int kbase = kt * 32 + kg * 8;
        if (valid) {
            v0 = *(const float4*)(xrow + kbase);
            v1 = *(const float4*)(xrow + kbase + 4);
        } else {
            v0.x = v0.y = v0.z = v0.w = 0.f;
            v1.x = v1.y = v1.z = v1.w = 0.f;
        }
        ushort8v u;
        u[0] = f2bf(v0.x); u[1] = f2bf(v0.y); u[2] = f2bf(v0.z); u[3] = f2bf(v0.w);
        u[4] = f2bf(v1.x); u[5] = f2bf(v1.y); u[6] = f2bf(v1.z); u[7] = f2bf(v1.w);
        afrag[kt] = __builtin_bit_cast(bf16x8, u);
    }

    for (int t = 0; t < 3; ++t) {
        __syncthreads();
        {
            const unsigned short* src = wt + t * 16384;
            #pragma unroll
            for (int it = 0; it < 8; ++it) {
                int i   = tid + it * 256;     // 16B chunk index, 0..2047
                int col = i >> 4;
                int ko  = i & 15;
                *(ushort8v*)&wS[col * 128 + (ko ^ (col & 7)) * 8] =
                    *(const ushort8v*)(src + i * 8);
            }
            if (tid < 128) biasS[tid] = ((t == 0) ? Qb : ((t == 1) ? Kb : Vb))[tid];
        }
        __syncthreads();

        f32x4 acc[8];
        #pragma unroll
        for (int c = 0; c < 8; ++c) acc[c] = (f32x4){0.f, 0.f, 0.f, 0.f};

        #pragma unroll
        for (int kt = 0; kt < 4; ++kt) {
            const int chunk = kt * 4 + kg;
            #pragma unroll
            for (int c = 0; c < 8; ++c) {
                const int col = c * 16 + arow;
                ushort8v bu = *(const ushort8v*)&wS[col * 128 + (chunk ^ (col & 7)) * 8];
                acc[c] = __builtin_amdgcn_mfma_f32_16x16x32_bf16(
                    afrag[kt], __builtin_bit_cast(bf16x8, bu), acc[c], 0, 0, 0);
            }
        }
        __syncthreads();

        #pragma unroll
        for (int c = 0; c < 8; ++c) {
            const int col = c * 16 + arow;
            const float b = biasS[col];
            #pragma unroll
            for (int r = 0; r < 4; ++r) {
                const int orow = w * 16 + kg * 4 + r;
                cS[orow * 144 + col] = f2bf(acc[c][r] + b);
            }
        }
        __syncthreads();

        #pragma unroll
        for (int it = 0; it < 4; ++it) {
            int i    = tid + it * 256;        // 0..1023: row*16 + 16B chunk
            int orow = i >> 4;
            int ch   = i & 15;
            int node = node0 + orow;
            if (node < N_NODES)
                *(ushort8v*)(qkv + (size_t)node * 384 + t * 128 + ch * 8) =
                    *(const ushort8v*)&cS[orow * 144 + ch * 8];
        }
    }
}

// ---- Clique contraction + fused scatter to A1 AND A0 (via the clique's 3 edges) ----
// 16 lanes per clique. A0 goes to 4 contention-spreading copies in ws.
__global__ __launch_bounds__(256) void clique_kernel(
    const unsigned short* __restrict__ qkv,
    const int* __restrict__ tci,      // [3][N_CLIQUES]
    const int* __restrict__ d1row1,   // [3*N_CLIQUES] clique -> edge ids
    const int* __restrict__ d0row1,   // [2*N_EDGES]   edge -> node ids
    float* __restrict__ outA1,
    float* __restrict__ outA2,
    float* __restrict__ a0c)          // [4][N_NODES] partial A0 accumulators
{
    const int tid = threadIdx.x;
    const int lane16 = tid & 15;
    const int cliq = (blockIdx.x * 256 + tid) >> 4;   // grid exact: 15625*16 = 250000

    const int ni = tci[cliq];
    const int nj = tci[N_CLIQUES + cliq];
    const int nk = tci[2 * N_CLIQUES + cliq];
    const int d0 = lane16 * 8;

    const ushort8v qi = *(const ushort8v*)(qkv + (size_t)ni * 384 +       d0);
    const ushort8v ki = *(const ushort8v*)(qkv + (size_t)ni * 384 + 128 + d0);
    const ushort8v vi = *(const ushort8v*)(qkv + (size_t)ni * 384 + 256 + d0);
    const ushort8v qj = *(const ushort8v*)(qkv + (size_t)nj * 384 +       d0);
    const ushort8v kj = *(const ushort8v*)(qkv + (size_t)nj * 384 + 128 + d0);
    const ushort8v vj = *(const ushort8v*)(qkv + (size_t)nj * 384 + 256 + d0);
    const ushort8v qk = *(const ushort8v*)(qkv + (size_t)nk * 384 +       d0);
    const ushort8v kk = *(const ushort8v*)(qkv + (size_t)nk * 384 + 128 + d0);
    const ushort8v vk = *(const ushort8v*)(qkv + (size_t)nk * 384 + 256 + d0);

    float s = 0.f;
    #pragma unroll
    for (int d = 0; d < 8; ++d) {
        float Qi = bf2f(qi[d]), Qj = bf2f(qj[d]), Qk = bf2f(qk[d]);
        float Ki = bf2f(ki[d]), Kj = bf2f(kj[d]), Kk = bf2f(kk[d]);
        float Vi = bf2f(vi[d]), Vj = bf2f(vj[d]), Vk = bf2f(vk[d]);
        s = fmaf(Qi, fmaf(Kj, Vk, Kk * Vj), s);
        s = fmaf(Qj, fmaf(Kk, Vi, Ki * Vk), s);
        s = fmaf(Qk, fmaf(Ki, Vj, Kj * Vi), s);
    }
    s += __shfl_xor(s, 1);
    s += __shfl_xor(s, 2);
    s += __shfl_xor(s, 4);
    s += __shfl_xor(s, 8);

    float score = expf(s * (1.0f / 24.0f));
    if (lane16 == 0) outA2[cliq] = score;
    if (lane16 < 3) {
        int e = d1row1[3 * cliq + lane16];
        atomicAdd(outA1 + e, score);
        int2 tg = *(const int2*)(d0row1 + 2 * (size_t)e);
        float* base = a0c + (size_t)(cliq & 3) * N_NODES;
        atomicAdd(base + tg.x, score);
        atomicAdd(base + tg.y, score);
    }
}

// ---- Combine the 4 A0 partial copies ----
__global__ __launch_bounds__(256) void combine_kernel(
    const float* __restrict__ a0c, float* __restrict__ outA0)
{
    int n = blockIdx.x * 256 + threadIdx.x;
    if (n < N_NODES)
        outA0[n] = (a0c[n] + a0c[N_NODES + n])
                 + (a0c[2 * N_NODES + n] + a0c[3 * N_NODES + n]);
}

extern "C" void kernel_launch(void* const* d_in, const int* in_sizes, int n_in,
                              void* d_out, int out_size, void* d_ws, size_t ws_size,
                              hipStream_t stream)
{
    const float* x  = (const float*)d_in[0];
    const int*   d0i = (const int*)d_in[2];     // [2][2*N_EDGES]
    const int*   tci = (const int*)d_in[3];     // [3][N_CLIQUES]
    const int*   d1i = (const int*)d_in[4];     // [2][3*N_CLIQUES]
    const float* Qw = (const float*)d_in[5];
    const float* Qb = (const float*)d_in[6];
    const float* Kw = (const float*)d_in[7];
    const float* Kb = (const float*)d_in[8];
    const float* Vw = (const float*)d_in[9];
    const float* Vb = (const float*)d_in[10];

    const int* d0row1 = d0i + 2 * (size_t)N_EDGES;
    const int* d1row1 = d1i + 3 * (size_t)N_CLIQUES;

    // ws: qkv bf16 76.8MB | wt bf16 96KB | a0c f32 [4][N_NODES] 1.6MB
    unsigned short* qkv = (unsigned short*)d_ws;
    unsigned short* wt  = qkv + (size_t)N_NODES * 384;
    float* a0c = (float*)(wt + 3 * 128 * 128);

    // outputs: FLOAT32, concatenated (diagA0, diagA1, diagA2)
    float* outA0 = (float*)d_out;
    float* outA1 = outA0 + N_NODES;
    float* outA2 = outA0 + N_NODES + N_EDGES;

    // zero: outA1 (atomic-accumulated in d_out) and the 4 A0 copies in ws
    zero_kernel<<<(N_EDGES + 255) / 256, 256, 0, stream>>>(outA1, N_EDGES);
    zero_kernel<<<(4 * N_NODES + 255) / 256, 256, 0, stream>>>(a0c, 4 * N_NODES);
    prep_weights<<<192, 256, 0, stream>>>(Qw, Kw, Vw, wt);
    proj_mfma<<<(N_NODES + 63) / 64, 256, 0, stream>>>(x, wt, Qb, Kb, Vb, qkv);
    clique_kernel<<<N_CLIQUES / 16, 256, 0, stream>>>(qkv, tci, d1row1, d0row1,
                                                      outA1, outA2, a0c);
    combine_kernel<<<(N_NODES + 255) / 256, 256, 0, stream>>>(a0c, outA0);
}

// Round 5
// 170.241 us; speedup vs baseline: 2.4767x; 1.0722x over previous
//
#include <hip/hip_runtime.h>

#define N_NODES   100000
#define N_EDGES   1600000
#define N_CLIQUES 250000

typedef unsigned short ushort8v __attribute__((ext_vector_type(8)));
typedef __bf16 bf16x8 __attribute__((ext_vector_type(8)));
typedef float f32x4 __attribute__((ext_vector_type(4)));
typedef float f32x2 __attribute__((ext_vector_type(2)));

__device__ __forceinline__ float bf2f(unsigned short u) {
    return __uint_as_float(((unsigned int)u) << 16);
}
__device__ __forceinline__ unsigned short f2bf(float f) {
    unsigned int u = __float_as_uint(f);
    u += 0x7FFFu + ((u >> 16) & 1u);
    return (unsigned short)(u >> 16);
}

// ---- prep: W [k][col] f32  ->  wt bf16 [t][col][k] (col-major for B-frag reads) ----
__global__ __launch_bounds__(256) void prep_weights(
    const float* __restrict__ Qw, const float* __restrict__ Kw,
    const float* __restrict__ Vw, unsigned short* __restrict__ wt)
{
    int idx = blockIdx.x * 256 + threadIdx.x;      // 3*128*128 = 49152
    int t = idx >> 14;
    int rem = idx & 16383;
    int col = rem >> 7;
    int k = rem & 127;
    const float* W = (t == 0) ? Qw : ((t == 1) ? Kw : Vw);
    wt[idx] = f2bf(W[k * 128 + col]);              // wt[t][col][k]
}

// ---- Projection via MFMA -> qkv fp8-e4m3 [node][3][128] ----
__global__ __launch_bounds__(256) void proj_mfma(
    const float* __restrict__ x,
    const unsigned short* __restrict__ wt,   // bf16 [3][128 col][128 k]
    const float* __restrict__ Qb, const float* __restrict__ Kb,
    const float* __restrict__ Vb,
    unsigned char* __restrict__ qkv8)
{
    __shared__ unsigned short wS[128 * 128];  // [col][k], 16B-chunk XOR swizzled, 32KB
    __shared__ unsigned short cS[64 * 144];   // C tile bf16 [row][col], padded stride
    __shared__ float biasS[128];

    const int tid  = threadIdx.x;
    const int lane = tid & 63;
    const int w    = tid >> 6;        // wave 0..3
    const int node0 = blockIdx.x * 64;
    const int arow = lane & 15;
    const int kg   = lane >> 4;       // 0..3 k-group

    bf16x8 afrag[4];
    const int myNode = node0 + w * 16 + arow;
    const bool valid = myNode < N_NODES;
    const float* xrow = x + (size_t)myNode * 128;
    #pragma unroll
    for (int kt = 0; kt < 4; ++kt) {
        float4 v0, v1;
        const int kbase = kt * 32 + kg * 8;
        if (valid) {
            v0 = *(const float4*)(xrow + kbase);
            v1 = *(const float4*)(xrow + kbase + 4);
        } else {
            v0.x = v0.y = v0.z = v0.w = 0.f;
            v1.x = v1.y = v1.z = v1.w = 0.f;
        }
        ushort8v u;
        u[0] = f2bf(v0.x); u[1] = f2bf(v0.y); u[2] = f2bf(v0.z); u[3] = f2bf(v0.w);
        u[4] = f2bf(v1.x); u[5] = f2bf(v1.y); u[6] = f2bf(v1.z); u[7] = f2bf(v1.w);
        afrag[kt] = __builtin_bit_cast(bf16x8, u);
    }

    for (int t = 0; t < 3; ++t) {
        __syncthreads();
        {
            const unsigned short* src = wt + t * 16384;
            #pragma unroll
            for (int it = 0; it < 8; ++it) {
                int i   = tid + it * 256;     // 16B chunk index, 0..2047
                int col = i >> 4;
                int ko  = i & 15;
                *(ushort8v*)&wS[col * 128 + (ko ^ (col & 7)) * 8] =
                    *(const ushort8v*)(src + i * 8);
            }
            if (tid < 128) biasS[tid] = ((t == 0) ? Qb : ((t == 1) ? Kb : Vb))[tid];
        }
        __syncthreads();

        f32x4 acc[8];
        #pragma unroll
        for (int c = 0; c < 8; ++c) acc[c] = (f32x4){0.f, 0.f, 0.f, 0.f};

        #pragma unroll
        for (int kt = 0; kt < 4; ++kt) {
            const int chunk = kt * 4 + kg;
            #pragma unroll
            for (int c = 0; c < 8; ++c) {
                const int col = c * 16 + arow;
                ushort8v bu = *(const ushort8v*)&wS[col * 128 + (chunk ^ (col & 7)) * 8];
                acc[c] = __builtin_amdgcn_mfma_f32_16x16x32_bf16(
                    afrag[kt], __builtin_bit_cast(bf16x8, bu), acc[c], 0, 0, 0);
            }
        }
        __syncthreads();

        // C frags -> LDS bf16 (+bias). D layout: col=lane&15, row=(lane>>4)*4+reg.
        #pragma unroll
        for (int c = 0; c < 8; ++c) {
            const int col = c * 16 + arow;
            const float b = biasS[col];
            #pragma unroll
            for (int r = 0; r < 4; ++r) {
                const int orow = w * 16 + kg * 4 + r;
                cS[orow * 144 + col] = f2bf(acc[c][r] + b);
            }
        }
        __syncthreads();

        // copy-out: pack 16 bf16 -> 16 fp8 per thread-iter, 16B stores
        #pragma unroll
        for (int it = 0; it < 2; ++it) {
            int i    = tid + it * 256;        // 0..511: row = i>>3, 16B chunk = i&7
            int orow = i >> 3;
            int ch   = i & 7;
            int node = node0 + orow;
            if (node < N_NODES) {
                const unsigned short* src = &cS[orow * 144 + ch * 16];
                unsigned int wo[4];
                #pragma unroll
                for (int q = 0; q < 4; ++q) {
                    float f0 = bf2f(src[q * 4 + 0]);
                    float f1 = bf2f(src[q * 4 + 1]);
                    float f2 = bf2f(src[q * 4 + 2]);
                    float f3 = bf2f(src[q * 4 + 3]);
                    int lo = __builtin_amdgcn_cvt_pk_fp8_f32(f0, f1, 0, false);
                    wo[q] = (unsigned int)__builtin_amdgcn_cvt_pk_fp8_f32(f2, f3, lo, true);
                }
                uint4 o; o.x = wo[0]; o.y = wo[1]; o.z = wo[2]; o.w = wo[3];
                *(uint4*)(qkv8 + (size_t)node * 384 + t * 128 + ch * 16) = o;
            }
        }
    }
}

#define DEC4(w_, a_) { f32x2 lo_ = __builtin_amdgcn_cvt_pk_f32_fp8((int)(w_), false); \
                       f32x2 hi_ = __builtin_amdgcn_cvt_pk_f32_fp8((int)(w_), true);  \
                       a_[0] = lo_[0]; a_[1] = lo_[1]; a_[2] = hi_[0]; a_[3] = hi_[1]; }

// ---- Clique contraction (fp8 gather) + fused scatter to A1 and A0 ----
// 8 lanes per clique, 16 dims/lane via 16B loads.
__global__ __launch_bounds__(256) void clique_kernel(
    const unsigned char* __restrict__ qkv8,
    const int* __restrict__ tci,      // [3][N_CLIQUES]
    const int* __restrict__ d1row1,   // [3*N_CLIQUES] clique -> edge ids
    const int* __restrict__ d0row1,   // [2*N_EDGES]   edge -> node ids
    float* __restrict__ outA1,
    float* __restrict__ outA2,
    float* __restrict__ a0c)          // [4][N_NODES] partial A0 accumulators
{
    const int tid = threadIdx.x;
    const int lane8 = tid & 7;
    const int cliq = (blockIdx.x * 256 + tid) >> 3;
    if (cliq >= N_CLIQUES) return;

    const int ni = tci[cliq];
    const int nj = tci[N_CLIQUES + cliq];
    const int nk = tci[2 * N_CLIQUES + cliq];
    const int d0 = lane8 * 16;

    const unsigned char* bi = qkv8 + (size_t)ni * 384 + d0;
    const unsigned char* bj = qkv8 + (size_t)nj * 384 + d0;
    const unsigned char* bk = qkv8 + (size_t)nk * 384 + d0;

    const uint4 rQi = *(const uint4*)(bi);
    const uint4 rKi = *(const uint4*)(bi + 128);
    const uint4 rVi = *(const uint4*)(bi + 256);
    const uint4 rQj = *(const uint4*)(bj);
    const uint4 rKj = *(const uint4*)(bj + 128);
    const uint4 rVj = *(const uint4*)(bj + 256);
    const uint4 rQk = *(const uint4*)(bk);
    const uint4 rKk = *(const uint4*)(bk + 128);
    const uint4 rVk = *(const uint4*)(bk + 256);

    float s = 0.f;
    #pragma unroll
    for (int c = 0; c < 4; ++c) {
        unsigned int wQi = ((const unsigned int*)&rQi)[c];
        unsigned int wKi = ((const unsigned int*)&rKi)[c];
        unsigned int wVi = ((const unsigned int*)&rVi)[c];
        unsigned int wQj = ((const unsigned int*)&rQj)[c];
        unsigned int wKj = ((const unsigned int*)&rKj)[c];
        unsigned int wVj = ((const unsigned int*)&rVj)[c];
        unsigned int wQk = ((const unsigned int*)&rQk)[c];
        unsigned int wKk = ((const unsigned int*)&rKk)[c];
        unsigned int wVk = ((const unsigned int*)&rVk)[c];
        float qi_[4], ki_[4], vi_[4], qj_[4], kj_[4], vj_[4], qk_[4], kk_[4], vk_[4];
        DEC4(wQi, qi_); DEC4(wKi, ki_); DEC4(wVi, vi_);
        DEC4(wQj, qj_); DEC4(wKj, kj_); DEC4(wVj, vj_);
        DEC4(wQk, qk_); DEC4(wKk, kk_); DEC4(wVk, vk_);
        #pragma unroll
        for (int d = 0; d < 4; ++d) {
            s = fmaf(qi_[d], fmaf(kj_[d], vk_[d], kk_[d] * vj_[d]), s);
            s = fmaf(qj_[d], fmaf(kk_[d], vi_[d], ki_[d] * vk_[d]), s);
            s = fmaf(qk_[d], fmaf(ki_[d], vj_[d], kj_[d] * vi_[d]), s);
        }
    }
    s += __shfl_xor(s, 1);
    s += __shfl_xor(s, 2);
    s += __shfl_xor(s, 4);

    float score = expf(s * (1.0f / 24.0f));
    if (lane8 == 0) outA2[cliq] = score;
    if (lane8 < 3) {
        int e = d1row1[3 * cliq + lane8];
        atomicAdd(outA1 + e, score);
        int2 tg = *(const int2*)(d0row1 + 2 * (size_t)e);
        float* base = a0c + (size_t)(cliq & 3) * N_NODES;
        atomicAdd(base + tg.x, score);
        atomicAdd(base + tg.y, score);
    }
}

// ---- Combine the 4 A0 partial copies ----
__global__ __launch_bounds__(256) void combine_kernel(
    const float* __restrict__ a0c, float* __restrict__ outA0)
{
    int n = blockIdx.x * 256 + threadIdx.x;
    if (n < N_NODES)
        outA0[n] = (a0c[n] + a0c[N_NODES + n])
                 + (a0c[2 * N_NODES + n] + a0c[3 * N_NODES + n]);
}

extern "C" void kernel_launch(void* const* d_in, const int* in_sizes, int n_in,
                              void* d_out, int out_size, void* d_ws, size_t ws_size,
                              hipStream_t stream)
{
    const float* x  = (const float*)d_in[0];
    const int*   d0i = (const int*)d_in[2];     // [2][2*N_EDGES]
    const int*   tci = (const int*)d_in[3];     // [3][N_CLIQUES]
    const int*   d1i = (const int*)d_in[4];     // [2][3*N_CLIQUES]
    const float* Qw = (const float*)d_in[5];
    const float* Qb = (const float*)d_in[6];
    const float* Kw = (const float*)d_in[7];
    const float* Kb = (const float*)d_in[8];
    const float* Vw = (const float*)d_in[9];
    const float* Vb = (const float*)d_in[10];

    const int* d0row1 = d0i + 2 * (size_t)N_EDGES;
    const int* d1row1 = d1i + 3 * (size_t)N_CLIQUES;

    // ws: qkv8 fp8 [100000][384] = 38.4MB | wt bf16 96KB | a0c f32 [4][N_NODES] 1.6MB
    unsigned char* qkv8 = (unsigned char*)d_ws;
    unsigned short* wt  = (unsigned short*)(qkv8 + (size_t)N_NODES * 384);
    float* a0c = (float*)(wt + 3 * 128 * 128);

    // outputs: FLOAT32, concatenated (diagA0, diagA1, diagA2)
    float* outA0 = (float*)d_out;
    float* outA1 = outA0 + N_NODES;
    float* outA2 = outA0 + N_NODES + N_EDGES;

    hipMemsetAsync(outA1, 0, (size_t)N_EDGES * 4, stream);
    hipMemsetAsync(a0c, 0, (size_t)4 * N_NODES * 4, stream);
    prep_weights<<<192, 256, 0, stream>>>(Qw, Kw, Vw, wt);
    proj_mfma<<<(N_NODES + 63) / 64, 256, 0, stream>>>(x, wt, Qb, Kb, Vb, qkv8);
    clique_kernel<<<(N_CLIQUES * 8 + 255) / 256, 256, 0, stream>>>(
        qkv8, tci, d1row1, d0row1, outA1, outA2, a0c);
    combine_kernel<<<(N_NODES + 255) / 256, 256, 0, stream>>>(a0c, outA0);
}

// Round 6
// 169.818 us; speedup vs baseline: 2.4828x; 1.0025x over previous
//
#include <hip/hip_runtime.h>

#define N_NODES   100000
#define N_EDGES   1600000
#define N_CLIQUES 250000

typedef unsigned short ushort8v __attribute__((ext_vector_type(8)));
typedef __bf16 bf16x8 __attribute__((ext_vector_type(8)));
typedef float f32x4 __attribute__((ext_vector_type(4)));
typedef float f32x2 __attribute__((ext_vector_type(2)));

__device__ __forceinline__ float bf2f(unsigned short u) {
    return __uint_as_float(((unsigned int)u) << 16);
}
__device__ __forceinline__ unsigned short f2bf(float f) {
    unsigned int u = __float_as_uint(f);
    u += 0x7FFFu + ((u >> 16) & 1u);
    return (unsigned short)(u >> 16);
}

// Hardware XCD id (0..7 on MI355X). Wave-uniform; guide m09-verified readable.
__device__ __forceinline__ int get_xcc_id() {
    unsigned int x;
    asm volatile("s_getreg_b32 %0, hwreg(HW_REG_XCC_ID)" : "=s"(x));
    return (int)(x & 7u);
}

// ---- prep: W [k][col] f32  ->  wt bf16 [t][col][k] (col-major for B-frag reads) ----
__global__ __launch_bounds__(256) void prep_weights(
    const float* __restrict__ Qw, const float* __restrict__ Kw,
    const float* __restrict__ Vw, unsigned short* __restrict__ wt)
{
    int idx = blockIdx.x * 256 + threadIdx.x;      // 3*128*128 = 49152
    int t = idx >> 14;
    int rem = idx & 16383;
    int col = rem >> 7;
    int k = rem & 127;
    const float* W = (t == 0) ? Qw : ((t == 1) ? Kw : Vw);
    wt[idx] = f2bf(W[k * 128 + col]);              // wt[t][col][k]
}

// ---- Projection via MFMA -> qkv fp8-e4m3 [node][3][128] ----
__global__ __launch_bounds__(256) void proj_mfma(
    const float* __restrict__ x,
    const unsigned short* __restrict__ wt,   // bf16 [3][128 col][128 k]
    const float* __restrict__ Qb, const float* __restrict__ Kb,
    const float* __restrict__ Vb,
    unsigned char* __restrict__ qkv8)
{
    __shared__ unsigned short wS[128 * 128];  // [col][k], 16B-chunk XOR swizzled, 32KB
    __shared__ unsigned short cS[64 * 144];   // C tile bf16 [row][col], padded stride
    __shared__ float biasS[128];

    const int tid  = threadIdx.x;
    const int lane = tid & 63;
    const int w    = tid >> 6;        // wave 0..3
    const int node0 = blockIdx.x * 64;
    const int arow = lane & 15;
    const int kg   = lane >> 4;       // 0..3 k-group

    bf16x8 afrag[4];
    const int myNode = node0 + w * 16 + arow;
    const bool valid = myNode < N_NODES;
    const float* xrow = x + (size_t)myNode * 128;
    #pragma unroll
    for (int kt = 0; kt < 4; ++kt) {
        float4 v0, v1;
        const int kbase = kt * 32 + kg * 8;
        if (valid) {
            v0 = *(const float4*)(xrow + kbase);
            v1 = *(const float4*)(xrow + kbase + 4);
        } else {
            v0.x = v0.y = v0.z = v0.w = 0.f;
            v1.x = v1.y = v1.z = v1.w = 0.f;
        }
        ushort8v u;
        u[0] = f2bf(v0.x); u[1] = f2bf(v0.y); u[2] = f2bf(v0.z); u[3] = f2bf(v0.w);
        u[4] = f2bf(v1.x); u[5] = f2bf(v1.y); u[6] = f2bf(v1.z); u[7] = f2bf(v1.w);
        afrag[kt] = __builtin_bit_cast(bf16x8, u);
    }

    for (int t = 0; t < 3; ++t) {
        __syncthreads();
        {
            const unsigned short* src = wt + t * 16384;
            #pragma unroll
            for (int it = 0; it < 8; ++it) {
                int i   = tid + it * 256;     // 16B chunk index, 0..2047
                int col = i >> 4;
                int ko  = i & 15;
                *(ushort8v*)&wS[col * 128 + (ko ^ (col & 7)) * 8] =
                    *(const ushort8v*)(src + i * 8);
            }
            if (tid < 128) biasS[tid] = ((t == 0) ? Qb : ((t == 1) ? Kb : Vb))[tid];
        }
        __syncthreads();

        f32x4 acc[8];
        #pragma unroll
        for (int c = 0; c < 8; ++c) acc[c] = (f32x4){0.f, 0.f, 0.f, 0.f};

        #pragma unroll
        for (int kt = 0; kt < 4; ++kt) {
            const int chunk = kt * 4 + kg;
            #pragma unroll
            for (int c = 0; c < 8; ++c) {
                const int col = c * 16 + arow;
                ushort8v bu = *(const ushort8v*)&wS[col * 128 + (chunk ^ (col & 7)) * 8];
                acc[c] = __builtin_amdgcn_mfma_f32_16x16x32_bf16(
                    afrag[kt], __builtin_bit_cast(bf16x8, bu), acc[c], 0, 0, 0);
            }
        }
        __syncthreads();

        // C frags -> LDS bf16 (+bias). D layout: col=lane&15, row=(lane>>4)*4+reg.
        #pragma unroll
        for (int c = 0; c < 8; ++c) {
            const int col = c * 16 + arow;
            const float b = biasS[col];
            #pragma unroll
            for (int r = 0; r < 4; ++r) {
                const int orow = w * 16 + kg * 4 + r;
                cS[orow * 144 + col] = f2bf(acc[c][r] + b);
            }
        }
        __syncthreads();

        // copy-out: pack 16 bf16 -> 16 fp8 per thread-iter, 16B stores
        #pragma unroll
        for (int it = 0; it < 2; ++it) {
            int i    = tid + it * 256;        // 0..511: row = i>>3, 16B chunk = i&7
            int orow = i >> 3;
            int ch   = i & 7;
            int node = node0 + orow;
            if (node < N_NODES) {
                const unsigned short* src = &cS[orow * 144 + ch * 16];
                unsigned int wo[4];
                #pragma unroll
                for (int q = 0; q < 4; ++q) {
                    float f0 = bf2f(src[q * 4 + 0]);
                    float f1 = bf2f(src[q * 4 + 1]);
                    float f2 = bf2f(src[q * 4 + 2]);
                    float f3 = bf2f(src[q * 4 + 3]);
                    int lo = __builtin_amdgcn_cvt_pk_fp8_f32(f0, f1, 0, false);
                    wo[q] = (unsigned int)__builtin_amdgcn_cvt_pk_fp8_f32(f2, f3, lo, true);
                }
                uint4 o; o.x = wo[0]; o.y = wo[1]; o.z = wo[2]; o.w = wo[3];
                *(uint4*)(qkv8 + (size_t)node * 384 + t * 128 + ch * 16) = o;
            }
        }
    }
}

#define DEC4(w_, a_) { f32x2 lo_ = __builtin_amdgcn_cvt_pk_f32_fp8((int)(w_), false); \
                       f32x2 hi_ = __builtin_amdgcn_cvt_pk_f32_fp8((int)(w_), true);  \
                       a_[0] = lo_[0]; a_[1] = lo_[1]; a_[2] = hi_[0]; a_[3] = hi_[1]; }

// ---- Clique contraction (fp8 gather) + fused scatter ----
// A1: device-scope atomics (750K, hidden under gather).
// A0: XCD-local L2 atomics into 8 per-XCD copies (no memory-side atomic traffic).
__global__ __launch_bounds__(256) void clique_kernel(
    const unsigned char* __restrict__ qkv8,
    const int* __restrict__ tci,      // [3][N_CLIQUES]
    const int* __restrict__ d1row1,   // [3*N_CLIQUES] clique -> edge ids
    const int* __restrict__ d0row1,   // [2*N_EDGES]   edge -> node ids
    float* __restrict__ outA1,
    float* __restrict__ outA2,
    float* __restrict__ a0x)          // [8][N_NODES] per-XCD A0 accumulators
{
    const int tid = threadIdx.x;
    const int lane8 = tid & 7;
    const int cliq = (blockIdx.x * 256 + tid) >> 3;
    if (cliq >= N_CLIQUES) return;

    const int ni = tci[cliq];
    const int nj = tci[N_CLIQUES + cliq];
    const int nk = tci[2 * N_CLIQUES + cliq];
    const int d0 = lane8 * 16;

    const unsigned char* bi = qkv8 + (size_t)ni * 384 + d0;
    const unsigned char* bj = qkv8 + (size_t)nj * 384 + d0;
    const unsigned char* bk = qkv8 + (size_t)nk * 384 + d0;

    const uint4 rQi = *(const uint4*)(bi);
    const uint4 rKi = *(const uint4*)(bi + 128);
    const uint4 rVi = *(const uint4*)(bi + 256);
    const uint4 rQj = *(const uint4*)(bj);
    const uint4 rKj = *(const uint4*)(bj + 128);
    const uint4 rVj = *(const uint4*)(bj + 256);
    const uint4 rQk = *(const uint4*)(bk);
    const uint4 rKk = *(const uint4*)(bk + 128);
    const uint4 rVk = *(const uint4*)(bk + 256);

    float s = 0.f;
    #pragma unroll
    for (int c = 0; c < 4; ++c) {
        unsigned int wQi = ((const unsigned int*)&rQi)[c];
        unsigned int wKi = ((const unsigned int*)&rKi)[c];
        unsigned int wVi = ((const unsigned int*)&rVi)[c];
        unsigned int wQj = ((const unsigned int*)&rQj)[c];
        unsigned int wKj = ((const unsigned int*)&rKj)[c];
        unsigned int wVj = ((const unsigned int*)&rVj)[c];
        unsigned int wQk = ((const unsigned int*)&rQk)[c];
        unsigned int wKk = ((const unsigned int*)&rKk)[c];
        unsigned int wVk = ((const unsigned int*)&rVk)[c];
        float qi_[4], ki_[4], vi_[4], qj_[4], kj_[4], vj_[4], qk_[4], kk_[4], vk_[4];
        DEC4(wQi, qi_); DEC4(wKi, ki_); DEC4(wVi, vi_);
        DEC4(wQj, qj_); DEC4(wKj, kj_); DEC4(wVj, vj_);
        DEC4(wQk, qk_); DEC4(wKk, kk_); DEC4(wVk, vk_);
        #pragma unroll
        for (int d = 0; d < 4; ++d) {
            s = fmaf(qi_[d], fmaf(kj_[d], vk_[d], kk_[d] * vj_[d]), s);
            s = fmaf(qj_[d], fmaf(kk_[d], vi_[d], ki_[d] * vk_[d]), s);
            s = fmaf(qk_[d], fmaf(ki_[d], vj_[d], kj_[d] * vi_[d]), s);
        }
    }
    s += __shfl_xor(s, 1);
    s += __shfl_xor(s, 2);
    s += __shfl_xor(s, 4);

    float score = expf(s * (1.0f / 24.0f));
    if (lane8 == 0) outA2[cliq] = score;
    if (lane8 < 3) {
        int e = d1row1[3 * cliq + lane8];
        atomicAdd(outA1 + e, score);                       // device scope (IC)
        int2 tg = *(const int2*)(d0row1 + 2 * (size_t)e);
        float* base = a0x + (size_t)get_xcc_id() * N_NODES; // private per-XCD copy
        __hip_atomic_fetch_add(base + tg.x, score,
                               __ATOMIC_RELAXED, __HIP_MEMORY_SCOPE_WORKGROUP);
        __hip_atomic_fetch_add(base + tg.y, score,
                               __ATOMIC_RELAXED, __HIP_MEMORY_SCOPE_WORKGROUP);
    }
}

// ---- Combine the 8 per-XCD A0 copies ----
__global__ __launch_bounds__(256) void combine_kernel(
    const float* __restrict__ a0x, float* __restrict__ outA0)
{
    int n = blockIdx.x * 256 + threadIdx.x;
    if (n < N_NODES) {
        float s = 0.f;
        #pragma unroll
        for (int c = 0; c < 8; ++c) s += a0x[(size_t)c * N_NODES + n];
        outA0[n] = s;
    }
}

extern "C" void kernel_launch(void* const* d_in, const int* in_sizes, int n_in,
                              void* d_out, int out_size, void* d_ws, size_t ws_size,
                              hipStream_t stream)
{
    const float* x  = (const float*)d_in[0];
    const int*   d0i = (const int*)d_in[2];     // [2][2*N_EDGES]
    const int*   tci = (const int*)d_in[3];     // [3][N_CLIQUES]
    const int*   d1i = (const int*)d_in[4];     // [2][3*N_CLIQUES]
    const float* Qw = (const float*)d_in[5];
    const float* Qb = (const float*)d_in[6];
    const float* Kw = (const float*)d_in[7];
    const float* Kb = (const float*)d_in[8];
    const float* Vw = (const float*)d_in[9];
    const float* Vb = (const float*)d_in[10];

    const int* d0row1 = d0i + 2 * (size_t)N_EDGES;
    const int* d1row1 = d1i + 3 * (size_t)N_CLIQUES;

    // ws: qkv8 fp8 [100000][384] = 38.4MB | wt bf16 96KB | a0x f32 [8][N_NODES] 3.2MB
    unsigned char* qkv8 = (unsigned char*)d_ws;
    unsigned short* wt  = (unsigned short*)(qkv8 + (size_t)N_NODES * 384);
    float* a0x = (float*)(wt + 3 * 128 * 128);

    // outputs: FLOAT32, concatenated (diagA0, diagA1, diagA2)
    float* outA0 = (float*)d_out;
    float* outA1 = outA0 + N_NODES;
    float* outA2 = outA0 + N_NODES + N_EDGES;

    hipMemsetAsync(outA1, 0, (size_t)N_EDGES * 4, stream);
    hipMemsetAsync(a0x, 0, (size_t)8 * N_NODES * 4, stream);
    prep_weights<<<192, 256, 0, stream>>>(Qw, Kw, Vw, wt);
    proj_mfma<<<(N_NODES + 63) / 64, 256, 0, stream>>>(x, wt, Qb, Kb, Vb, qkv8);
    clique_kernel<<<(N_CLIQUES * 8 + 255) / 256, 256, 0, stream>>>(
        qkv8, tci, d1row1, d0row1, outA1, outA2, a0x);
    combine_kernel<<<(N_NODES + 255) / 256, 256, 0, stream>>>(a0x, outA0);
}